// Round 5
// baseline (15184.221 us; speedup 1.0000x reference)
//
#include <hip/hip_runtime.h>

// Decoder ODE-RNN (GRU + Euler-2 ODE + softmax emit). Inputs/outputs FLOAT32
// (confirmed: r1 bf16-read -> NaN; r3 f32 probs passed). The recurrence is
// chaotic (amplification ~1e5 of per-step rounding noise -> JAX-vs-np f32
// baseline disagreement ~0.35, threshold 2.8), so plain bf16 MFMA saturates
// at O(state) error. We therefore emulate f32 GEMM via bf16x3 splitting:
//   a = a_hi + a_mid + a_lo  (each bf16; repr error ~2^-27 rel)
//   A*B ~= hh + hm + mh + mm + hl + lh   (6 MFMAs, f32 accumulate)
// per-GEMM error ~ sqrt(K)*2^-24 — same class as np/JAX f32 GEMMs.
// LATENT=1024, INPUT=512, CLUSTER=256, N_UNITS=100 (pad 128), N_TRAJ=512, N_TP=64.

typedef __bf16 bf16_t;
typedef __bf16 bf16x8 __attribute__((ext_vector_type(8)));
typedef float  f32x4  __attribute__((ext_vector_type(4)));

#define BM 64
#define BN 64
#define BK 32
#define LDT 40   // padded LDS row stride: 80B -> max 2-way bank aliasing (free)

__device__ __forceinline__ float sigmoidf_(float x) { return 1.f / (1.f + expf(-x)); }

// flag-aware 8-float load from HARNESS inputs (f32 vs bf16 decided at runtime)
__device__ __forceinline__ void loadf8(const void* p, size_t idx, int isf32, float out[8]) {
  if (isf32) {
    const float* q = (const float*)p + idx;
    f32x4 a = *(const f32x4*)q;
    f32x4 b = *(const f32x4*)(q + 4);
    out[0]=a[0]; out[1]=a[1]; out[2]=a[2]; out[3]=a[3];
    out[4]=b[0]; out[5]=b[1]; out[6]=b[2]; out[7]=b[3];
  } else {
    bf16x8 v = *(const bf16x8*)((const bf16_t*)p + idx);
#pragma unroll
    for (int i = 0; i < 8; i++) out[i] = (float)v[i];
  }
}
__device__ __forceinline__ float loadf(const void* p, int idx, int isf32) {
  return isf32 ? ((const float*)p)[idx] : (float)((const bf16_t*)p)[idx];
}

__global__ void k_probe(const unsigned int* ts_raw, int* flag) {
  *flag = (ts_raw[0] == 0u) ? 1 : 0;   // 1 = f32 inputs, 0 = bf16 inputs
}

// ---------------- split-precision GEMM core: C[64x64] tile of A[M,K] * B.
// A: f32 row-major (internal). BT: f32 [N][K] (transposed weights, internal).
// CATX: A is concat(h[512,1024] f32, data[:,t,:] harness dtype) along K (K=1536).
template<bool CATX>
__device__ __forceinline__ void gemm3(
    const float* __restrict__ A, int lda,
    const void* __restrict__ X, int t, int isf32,   // x row m -> X + m*32768 + t*512
    const float* __restrict__ BT, int K,
    f32x4 acc[2][2])
{
  __shared__ __align__(16) bf16_t As[3][BM * LDT];
  __shared__ __align__(16) bf16_t Bs[3][BN * LDT];

  const int tid  = threadIdx.x;
  const int srow = tid >> 2;            // 0..63 staging row
  const int sk8  = (tid & 3) << 3;      // 0,8,16,24
  const int mBase = blockIdx.y * BM;
  const int nBase = blockIdx.x * BN;

  const int lane = tid & 63;
  const int wid  = tid >> 6;
  const int wm   = (wid & 1) * 32;
  const int wn   = (wid >> 1) * 32;
  const int q8   = (lane >> 4) << 3;    // 0,8,16,24
  const int l16  = lane & 15;

  f32x4 z = {0.f, 0.f, 0.f, 0.f};
#pragma unroll
  for (int i = 0; i < 2; i++)
#pragma unroll
    for (int j = 0; j < 2; j++) acc[i][j] = z;

  for (int k0 = 0; k0 < K; k0 += BK) {
    const int gk = k0 + sk8;
    float av[8], bv[8];
    if (CATX && gk >= 1024) {
      loadf8(X, (size_t)(mBase + srow) * 32768 + (size_t)t * 512 + (gk - 1024), isf32, av);
    } else {
      const float* q = A + (size_t)(mBase + srow) * lda + gk;
      *(f32x4*)&av[0] = *(const f32x4*)q;
      *(f32x4*)&av[4] = *(const f32x4*)(q + 4);
    }
    {
      const float* q = BT + (size_t)(nBase + srow) * K + gk;
      *(f32x4*)&bv[0] = *(const f32x4*)q;
      *(f32x4*)&bv[4] = *(const f32x4*)(q + 4);
    }
    bf16x8 ah, am, al, bh, bm, bl;
#pragma unroll
    for (int i = 0; i < 8; i++) {
      float v = av[i];
      bf16_t h = (bf16_t)v;  float r1 = v - (float)h;
      bf16_t m = (bf16_t)r1; float r2 = r1 - (float)m;
      bf16_t l = (bf16_t)r2;
      ah[i] = h; am[i] = m; al[i] = l;
      v = bv[i];
      h = (bf16_t)v;  r1 = v - (float)h;
      m = (bf16_t)r1; r2 = r1 - (float)m;
      l = (bf16_t)r2;
      bh[i] = h; bm[i] = m; bl[i] = l;
    }
    *(bf16x8*)&As[0][srow * LDT + sk8] = ah;
    *(bf16x8*)&As[1][srow * LDT + sk8] = am;
    *(bf16x8*)&As[2][srow * LDT + sk8] = al;
    *(bf16x8*)&Bs[0][srow * LDT + sk8] = bh;
    *(bf16x8*)&Bs[1][srow * LDT + sk8] = bm;
    *(bf16x8*)&Bs[2][srow * LDT + sk8] = bl;
    __syncthreads();

    bf16x8 a[2][3], b[2][3];
#pragma unroll
    for (int p = 0; p < 3; p++) {
      a[0][p] = *(const bf16x8*)&As[p][(wm +      l16) * LDT + q8];
      a[1][p] = *(const bf16x8*)&As[p][(wm + 16 + l16) * LDT + q8];
      b[0][p] = *(const bf16x8*)&Bs[p][(wn +      l16) * LDT + q8];
      b[1][p] = *(const bf16x8*)&Bs[p][(wn + 16 + l16) * LDT + q8];
    }
#pragma unroll
    for (int mi = 0; mi < 2; mi++)
#pragma unroll
      for (int ni = 0; ni < 2; ni++) {
        f32x4 c = acc[mi][ni];
        c = __builtin_amdgcn_mfma_f32_16x16x32_bf16(a[mi][0], b[ni][0], c, 0, 0, 0); // hh
        c = __builtin_amdgcn_mfma_f32_16x16x32_bf16(a[mi][0], b[ni][1], c, 0, 0, 0); // hm
        c = __builtin_amdgcn_mfma_f32_16x16x32_bf16(a[mi][1], b[ni][0], c, 0, 0, 0); // mh
        c = __builtin_amdgcn_mfma_f32_16x16x32_bf16(a[mi][1], b[ni][1], c, 0, 0, 0); // mm
        c = __builtin_amdgcn_mfma_f32_16x16x32_bf16(a[mi][0], b[ni][2], c, 0, 0, 0); // hl
        c = __builtin_amdgcn_mfma_f32_16x16x32_bf16(a[mi][2], b[ni][0], c, 0, 0, 0); // lh
        acc[mi][ni] = c;
      }
    __syncthreads();
  }
}

#define EPI_COORDS \
  const int lane = threadIdx.x & 63; \
  const int wid  = threadIdx.x >> 6; \
  const int row0 = blockIdx.y * BM + (wid & 1) * 32 + ((lane >> 4) << 2); \
  const int col0 = blockIdx.x * BN + (wid >> 1) * 32 + (lane & 15);

// ---------------- gates: u = sigmoid([h,x]@Wu + bu) ; r likewise ; hr = h * r (all f32)
__global__ __launch_bounds__(256) void k_gates(
    const float* __restrict__ hA, const void* __restrict__ data, int t,
    const float* __restrict__ WurT,
    const void* __restrict__ bu, const void* __restrict__ br,
    float* __restrict__ u_f32, float* __restrict__ hrf, const int* __restrict__ flg)
{
  const int isf32 = *flg;
  f32x4 acc[2][2];
  gemm3<true>(hA, 1024, data, t, isf32, WurT, 1536, acc);
  EPI_COORDS
#pragma unroll
  for (int mi = 0; mi < 2; mi++)
#pragma unroll
    for (int ni = 0; ni < 2; ni++)
#pragma unroll
      for (int r = 0; r < 4; r++) {
        int m = row0 + mi * 16 + r;
        int n = col0 + ni * 16;
        float v = acc[mi][ni][r];
        if (n < 1024) {
          u_f32[m * 1024 + n] = sigmoidf_(v + loadf(bu, n, isf32));
        } else {
          int nn = n - 1024;
          float rr = sigmoidf_(v + loadf(br, nn, isf32));
          hrf[m * 1024 + nn] = hA[m * 1024 + nn] * rr;
        }
      }
}

// ---------------- candidate + GRU blend: n = [hr,x]@Wn + bn ; h1 = (1-u)*n + u*h
__global__ __launch_bounds__(256) void k_cand(
    const float* __restrict__ hrf, const void* __restrict__ data, int t,
    const float* __restrict__ WnT, const void* __restrict__ bn,
    const float* __restrict__ u_f32, const float* __restrict__ h_f32,
    float* __restrict__ h1_f32, const int* __restrict__ flg)
{
  const int isf32 = *flg;
  f32x4 acc[2][2];
  gemm3<true>(hrf, 1024, data, t, isf32, WnT, 1536, acc);
  EPI_COORDS
#pragma unroll
  for (int mi = 0; mi < 2; mi++)
#pragma unroll
    for (int ni = 0; ni < 2; ni++)
#pragma unroll
      for (int r = 0; r < 4; r++) {
        int m = row0 + mi * 16 + r;
        int n = col0 + ni * 16;
        int idx = m * 1024 + n;
        float nv = acc[mi][ni][r] + loadf(bn, n, isf32);
        float u = u_f32[idx];
        float h1 = (1.f - u) * nv + u * h_f32[idx];
        h1 = fminf(fmaxf(h1, -1e6f), 1e6f);   // insurance clamp (never engages if correct)
        h1_f32[idx] = h1;
      }
}

// ---------------- euler stage A: tbf = tanh(h@W1 + b1), N padded to 128 (cols>=100 are 0)
__global__ __launch_bounds__(256) void k_tanh(
    const float* __restrict__ hin, const float* __restrict__ W1T,
    const void* __restrict__ b1, float* __restrict__ tbf, const int* __restrict__ flg)
{
  const int isf32 = *flg;
  f32x4 acc[2][2];
  gemm3<false>(hin, 1024, nullptr, 0, 0, W1T, 1024, acc);
  EPI_COORDS
#pragma unroll
  for (int mi = 0; mi < 2; mi++)
#pragma unroll
    for (int ni = 0; ni < 2; ni++)
#pragma unroll
      for (int r = 0; r < 4; r++) {
        int m = row0 + mi * 16 + r;
        int n = col0 + ni * 16;
        float b = (n < 100) ? loadf(b1, n, isf32) : 0.f;
        tbf[m * 128 + n] = tanhf(acc[mi][ni][r] + b);
      }
}

// ---------------- euler stage B: h_out = h_prev + (dt/2)*(tbf@W2 + b2)
template<bool WRITE_STATES>
__global__ __launch_bounds__(256) void k_euler(
    const float* __restrict__ tbf, const float* __restrict__ W2T,
    const void* __restrict__ b2, const void* __restrict__ ts, int t,
    const float* __restrict__ hprev_f32,
    float* __restrict__ hout_f32, float* __restrict__ states, const int* __restrict__ flg)
{
  const int isf32 = *flg;
  f32x4 acc[2][2];
  gemm3<false>(tbf, 128, nullptr, 0, 0, W2T, 128, acc);
  float dt = loadf(ts, t + 1, isf32) - loadf(ts, t, isf32);
  float s = 0.5f * dt;
  EPI_COORDS
#pragma unroll
  for (int mi = 0; mi < 2; mi++)
#pragma unroll
    for (int ni = 0; ni < 2; ni++)
#pragma unroll
      for (int r = 0; r < 4; r++) {
        int m = row0 + mi * 16 + r;
        int n = col0 + ni * 16;
        int idx = m * 1024 + n;
        float hv = hprev_f32[idx] + s * (acc[mi][ni][r] + loadf(b2, n, isf32));
        hv = fminf(fmaxf(hv, -1e6f), 1e6f);   // insurance clamp
        hout_f32[idx] = hv;
        if (WRITE_STATES)
          states[((size_t)t * 512 + m) * 1024 + n] = hv;   // f32 output
      }
}

// ---------------- emit: logits = h@We + be
__global__ __launch_bounds__(256) void k_emit(
    const float* __restrict__ hb, const float* __restrict__ WeT,
    const void* __restrict__ be, float* __restrict__ logits, const int* __restrict__ flg)
{
  const int isf32 = *flg;
  f32x4 acc[2][2];
  gemm3<false>(hb, 1024, nullptr, 0, 0, WeT, 1024, acc);
  EPI_COORDS
#pragma unroll
  for (int mi = 0; mi < 2; mi++)
#pragma unroll
    for (int ni = 0; ni < 2; ni++)
#pragma unroll
      for (int r = 0; r < 4; r++) {
        int m = row0 + mi * 16 + r;
        int n = col0 + ni * 16;
        logits[m * 256 + n] = acc[mi][ni][r] + loadf(be, n, isf32);
      }
}

// ---------------- row softmax over 256 (f32 output)
__global__ __launch_bounds__(256) void k_softmax(
    const float* __restrict__ logits, float* __restrict__ probs, int t)
{
  int m = blockIdx.x;
  int j = threadIdx.x;
  float v = logits[m * 256 + j];
  __shared__ float red[256];
  red[j] = v;
  __syncthreads();
  for (int s = 128; s > 0; s >>= 1) {
    if (j < s) red[j] = fmaxf(red[j], red[j + s]);
    __syncthreads();
  }
  float mx = red[0];
  __syncthreads();
  float e = expf(v - mx);
  red[j] = e;
  __syncthreads();
  for (int s = 128; s > 0; s >>= 1) {
    if (j < s) red[j] += red[j + s];
    __syncthreads();
  }
  probs[((size_t)t * 512 + m) * 256 + j] = e / red[0];
}

// ---------------- weight transpose into W^T [Npad][Kpad] f32, zero-padded
__global__ void k_transpose(const void* __restrict__ src, float* __restrict__ dst,
                            int K, int N, int Kpad, const int* __restrict__ flg)
{
  const int isf32 = *flg;
  int k = blockIdx.x * 256 + threadIdx.x;
  if (k >= Kpad) return;
  int n = blockIdx.y;  // < Npad
  float v = 0.f;
  if (k < K && n < N) v = loadf(src, k * N + n, isf32);
  dst[(size_t)n * Kpad + k] = v;
}

extern "C" void kernel_launch(void* const* d_in, const int* in_sizes, int n_in,
                              void* d_out, int out_size, void* d_ws, size_t ws_size,
                              hipStream_t stream) {
  const void* data = d_in[0];
  const void* ts   = d_in[1];
  const void* Wu   = d_in[2];
  const void* bu   = d_in[3];
  const void* Wr   = d_in[4];
  const void* br   = d_in[5];
  const void* Wn   = d_in[6];
  const void* bn   = d_in[7];
  const void* W1   = d_in[8];
  const void* b1   = d_in[9];
  const void* W2   = d_in[10];
  const void* b2   = d_in[11];
  const void* We   = d_in[12];
  const void* be   = d_in[13];

  float* out_probs  = (float*)d_out;
  float* out_states = (float*)d_out + (size_t)63 * 512 * 256;

  char* p = (char*)d_ws;
  auto carve = [&](size_t bytes) { char* r = p; p += (bytes + 255) & ~255ull; return (void*)r; };
  int*   flg  = (int*)carve(256);
  float* WurT = (float*)carve((size_t)2048 * 1536 * 4);
  float* WnT  = (float*)carve((size_t)1024 * 1536 * 4);
  float* W1T  = (float*)carve((size_t)128 * 1024 * 4);
  float* W2T  = (float*)carve((size_t)1024 * 128 * 4);
  float* WeT  = (float*)carve((size_t)256 * 1024 * 4);
  float* P0f  = (float*)carve((size_t)512 * 1024 * 4);
  float* P1f  = (float*)carve((size_t)512 * 1024 * 4);
  float* P2f  = (float*)carve((size_t)512 * 1024 * 4);
  float* hrf  = (float*)carve((size_t)512 * 1024 * 4);
  float* uf   = (float*)carve((size_t)512 * 1024 * 4);
  float* tbf  = (float*)carve((size_t)512 * 128 * 4);
  float* lg   = (float*)carve((size_t)512 * 256 * 4);

  (void)hipMemsetAsync(P0f, 0, (size_t)512 * 1024 * 4, stream);  // h0 = 0

  dim3 b256(256);
  k_probe<<<1, 1, 0, stream>>>((const unsigned int*)ts, flg);

  k_transpose<<<dim3(6, 1024), b256, 0, stream>>>(Wu, WurT,               1536, 1024, 1536, flg);
  k_transpose<<<dim3(6, 1024), b256, 0, stream>>>(Wr, WurT + 1024 * 1536, 1536, 1024, 1536, flg);
  k_transpose<<<dim3(6, 1024), b256, 0, stream>>>(Wn, WnT,                1536, 1024, 1536, flg);
  k_transpose<<<dim3(4, 128),  b256, 0, stream>>>(W1, W1T,                1024,  100, 1024, flg);
  k_transpose<<<dim3(1, 1024), b256, 0, stream>>>(W2, W2T,                 100, 1024,  128, flg);
  k_transpose<<<dim3(4, 256),  b256, 0, stream>>>(We, WeT,                1024,  256, 1024, flg);

  for (int t = 0; t < 63; t++) {
    // chain: P0 (h) -> gates/cand -> P1 -> euler1 -> P2 -> euler2 -> P0 (next h)
    k_gates<<<dim3(32, 8), b256, 0, stream>>>(P0f, data, t, WurT, bu, br, uf, hrf, flg);
    k_cand <<<dim3(16, 8), b256, 0, stream>>>(hrf, data, t, WnT, bn, uf, P0f, P1f, flg);
    k_tanh <<<dim3(2, 8),  b256, 0, stream>>>(P1f, W1T, b1, tbf, flg);
    k_euler<false><<<dim3(16, 8), b256, 0, stream>>>(tbf, W2T, b2, ts, t, P1f, P2f, nullptr, flg);
    k_tanh <<<dim3(2, 8),  b256, 0, stream>>>(P2f, W1T, b1, tbf, flg);
    k_euler<true> <<<dim3(16, 8), b256, 0, stream>>>(tbf, W2T, b2, ts, t, P2f, P0f, out_states, flg);
    k_emit <<<dim3(4, 8),  b256, 0, stream>>>(P0f, WeT, be, lg, flg);
    k_softmax<<<512, b256, 0, stream>>>(lg, out_probs, t);
  }
}